// Round 7
// baseline (6567.542 us; speedup 1.0000x reference)
//
#include <hip/hip_runtime.h>
#include <hip/hip_bf16.h>

// ---------------------------------------------------------------------------
// SMN forward. B=512 U=10 L=50 E=200 H=200 V=50000
// ---------------------------------------------------------------------------

typedef __attribute__((ext_vector_type(8))) short short8v;   // 8 bf16 (4 VGPR)
typedef __attribute__((ext_vector_type(4))) float f32x4;

__device__ __forceinline__ float sigm(float x) { return 1.0f / (1.0f + __expf(-x)); }
__device__ __forceinline__ float tanhfast(float x) {
    float e = __expf(2.0f * x);
    return 1.0f - 2.0f / (e + 1.0f);
}
__device__ __forceinline__ float bl(unsigned x) { return __uint_as_float(x << 16); }
__device__ __forceinline__ float bh(unsigned x) { return __uint_as_float(x & 0xffff0000u); }
__device__ __forceinline__ unsigned packbf(float a, float b) {
    union { __hip_bfloat16 h[2]; unsigned u; } cv;
    cv.h[0] = __float2bfloat16(a); cv.h[1] = __float2bfloat16(b);
    return cv.u;
}

// ---------------------------------------------------------------------------
// MFMA GEMM: C16[M,N] = bf16(A[M,200] @ W[N,200]^T + bias)
// ---------------------------------------------------------------------------
__global__ __launch_bounds__(256)
void gemm_mfma(const void* __restrict__ Asrc, int a_bf16,
               const int* __restrict__ gidx,
               const float* __restrict__ W, const float* __restrict__ bias,
               __hip_bfloat16* __restrict__ C, int M, int N)
{
    __shared__ __hip_bfloat16 Al[64 * 232];
    __shared__ __hip_bfloat16 Bl[64 * 232];
    const int tid = threadIdx.x;
    const int m0 = blockIdx.x * 64, n0 = blockIdx.y * 64;

    for (int idx = tid; idx < 64 * 29; idx += 256) {
        int r = idx / 29, q = idx - r * 29;
        int k0 = q * 8, row = m0 + r;
        uint4 val = make_uint4(0, 0, 0, 0);
        if (k0 < 200 && row < M) {
            size_t ar = (size_t)(gidx ? gidx[row] : row) * 200 + k0;
            if (a_bf16) {
                val = *(const uint4*)((const __hip_bfloat16*)Asrc + ar);
            } else {
                const float* ap = (const float*)Asrc + ar;
                float4 f0 = *(const float4*)ap;
                float4 f1 = *(const float4*)(ap + 4);
                val.x = packbf(f0.x, f0.y); val.y = packbf(f0.z, f0.w);
                val.z = packbf(f1.x, f1.y); val.w = packbf(f1.z, f1.w);
            }
        }
        *(uint4*)(Al + r * 232 + k0) = val;
    }
    for (int idx = tid; idx < 64 * 29; idx += 256) {
        int r = idx / 29, q = idx - r * 29;
        int k0 = q * 8, row = n0 + r;
        uint4 val = make_uint4(0, 0, 0, 0);
        if (k0 < 200 && row < N) {
            const float* wp = W + (size_t)row * 200 + k0;
            float4 f0 = *(const float4*)wp;
            float4 f1 = *(const float4*)(wp + 4);
            val.x = packbf(f0.x, f0.y); val.y = packbf(f0.z, f0.w);
            val.z = packbf(f1.x, f1.y); val.w = packbf(f1.z, f1.w);
        }
        *(uint4*)(Bl + r * 232 + k0) = val;
    }
    __syncthreads();

    const int wid = tid >> 6, lane = tid & 63;
    const int wm = (wid >> 1) * 32, wn = (wid & 1) * 32;
    const int lrow = lane & 15, lk8 = (lane >> 4) * 8;
    f32x4 acc00 = {0.f, 0.f, 0.f, 0.f}, acc01 = {0.f, 0.f, 0.f, 0.f};
    f32x4 acc10 = {0.f, 0.f, 0.f, 0.f}, acc11 = {0.f, 0.f, 0.f, 0.f};
#pragma unroll
    for (int kk = 0; kk < 7; ++kk) {
        const int kb = kk * 32 + lk8;
        short8v a0 = *(const short8v*)(Al + (wm + lrow) * 232 + kb);
        short8v a1 = *(const short8v*)(Al + (wm + 16 + lrow) * 232 + kb);
        short8v b0 = *(const short8v*)(Bl + (wn + lrow) * 232 + kb);
        short8v b1 = *(const short8v*)(Bl + (wn + 16 + lrow) * 232 + kb);
        acc00 = __builtin_amdgcn_mfma_f32_16x16x32_bf16(a0, b0, acc00, 0, 0, 0);
        acc01 = __builtin_amdgcn_mfma_f32_16x16x32_bf16(a0, b1, acc01, 0, 0, 0);
        acc10 = __builtin_amdgcn_mfma_f32_16x16x32_bf16(a1, b0, acc10, 0, 0, 0);
        acc11 = __builtin_amdgcn_mfma_f32_16x16x32_bf16(a1, b1, acc11, 0, 0, 0);
    }
    const int drow = (lane >> 4) * 4, dcol = lane & 15;
#pragma unroll
    for (int fm = 0; fm < 2; ++fm) {
#pragma unroll
        for (int fn = 0; fn < 2; ++fn) {
            const f32x4 av = (fm == 0) ? (fn == 0 ? acc00 : acc01)
                                       : (fn == 0 ? acc10 : acc11);
            const int gcol = n0 + wn + fn * 16 + dcol;
            if (gcol >= N) continue;
            const float bs = bias ? bias[gcol] : 0.0f;
#pragma unroll
            for (int r = 0; r < 4; ++r) {
                const int grow = m0 + wm + fm * 16 + drow + r;
                if (grow >= M) continue;
                C[(size_t)grow * N + gcol] = __float2bfloat16(av[r] + bs);
            }
        }
    }
}

// ---------------------------------------------------------------------------
// Generic fp32 GEMM (small tails): C = act(A @ W^T + bias)
// ---------------------------------------------------------------------------
__global__ __launch_bounds__(256)
void gemm_tn(const void* __restrict__ Av, int a_bf16,
             const int* __restrict__ gidx, int gstride, int goff,
             const float* __restrict__ W, const float* __restrict__ bias,
             void* __restrict__ Cv, int c_bf16,
             int M, int N, int K, int act)
{
    __shared__ float As[16][64];
    __shared__ float Ws[16][64];
    const int tid = threadIdx.x;
    const int m0 = blockIdx.x * 64;
    const int n0 = blockIdx.y * 64;
    const int lr = tid >> 2;
    const int lk = (tid & 3) << 2;
    const int tx = tid & 15, ty = tid >> 4;

    float acc[4][4];
#pragma unroll
    for (int i = 0; i < 4; ++i)
#pragma unroll
        for (int j = 0; j < 4; ++j) acc[i][j] = 0.0f;

    const int am = m0 + lr;
    size_t arow_off = 0; bool avalid = (am < M);
    if (avalid) arow_off = (size_t)(gidx ? gidx[(size_t)am * gstride + goff] : am) * K;
    const float* arow32 = (const float*)Av + arow_off;
    const __hip_bfloat16* arow16 = (const __hip_bfloat16*)Av + arow_off;
    const int wn = n0 + lr;
    const float* wrow = (wn < N) ? (W + (size_t)wn * K) : nullptr;

    for (int kb = 0; kb < K; kb += 16) {
        const int k = kb + lk;
        float a0 = 0, a1 = 0, a2 = 0, a3 = 0, w0 = 0, w1 = 0, w2 = 0, w3 = 0;
        if (avalid) {
            if (a_bf16) {
                if (k + 3 < K) {
                    uint2 p = *(const uint2*)(arow16 + k);
                    a0 = bl(p.x); a1 = bh(p.x); a2 = bl(p.y); a3 = bh(p.y);
                } else {
                    if (k < K) a0 = __bfloat162float(arow16[k]);
                    if (k + 1 < K) a1 = __bfloat162float(arow16[k + 1]);
                    if (k + 2 < K) a2 = __bfloat162float(arow16[k + 2]);
                }
            } else {
                if (k + 3 < K) { float4 v = *(const float4*)(arow32 + k); a0 = v.x; a1 = v.y; a2 = v.z; a3 = v.w; }
                else { if (k < K) a0 = arow32[k]; if (k + 1 < K) a1 = arow32[k + 1]; if (k + 2 < K) a2 = arow32[k + 2]; }
            }
        }
        if (wrow) {
            if (k + 3 < K) { float4 v = *(const float4*)(wrow + k); w0 = v.x; w1 = v.y; w2 = v.z; w3 = v.w; }
            else { if (k < K) w0 = wrow[k]; if (k + 1 < K) w1 = wrow[k + 1]; if (k + 2 < K) w2 = wrow[k + 2]; }
        }
        __syncthreads();
        As[lk + 0][lr] = a0; As[lk + 1][lr] = a1; As[lk + 2][lr] = a2; As[lk + 3][lr] = a3;
        Ws[lk + 0][lr] = w0; Ws[lk + 1][lr] = w1; Ws[lk + 2][lr] = w2; Ws[lk + 3][lr] = w3;
        __syncthreads();
#pragma unroll
        for (int kk = 0; kk < 16; ++kk) {
            float4 av = *(const float4*)(&As[kk][ty << 2]);
            float4 wv = *(const float4*)(&Ws[kk][tx << 2]);
            float aa[4] = { av.x, av.y, av.z, av.w };
            float ww[4] = { wv.x, wv.y, wv.z, wv.w };
#pragma unroll
            for (int i = 0; i < 4; ++i)
#pragma unroll
                for (int j = 0; j < 4; ++j)
                    acc[i][j] = fmaf(aa[i], ww[j], acc[i][j]);
        }
    }

#pragma unroll
    for (int i = 0; i < 4; ++i) {
        const int row = m0 + (ty << 2) + i;
        if (row >= M) continue;
#pragma unroll
        for (int j = 0; j < 4; ++j) {
            const int col = n0 + (tx << 2) + j;
            if (col >= N) continue;
            float t = acc[i][j];
            if (bias) t += bias[col];
            if (act == 1) t = tanhfast(t);
            if (c_bf16) ((__hip_bfloat16*)Cv)[(size_t)row * N + col] = __float2bfloat16(t);
            else        ((float*)Cv)[(size_t)row * N + col] = t;
        }
    }
}

// ---------------------------------------------------------------------------
__global__ __launch_bounds__(256)
void transpose3(const float* __restrict__ Wu, const float* __restrict__ Wr,
                const float* __restrict__ Wf, float* __restrict__ Tu,
                float* __restrict__ Tr, float* __restrict__ Tf)
{
    int id = blockIdx.x * 256 + threadIdx.x;
    if (id >= 360000) return;
    int tab = id / 120000, r = id - tab * 120000;
    int e = r / 600, j = r - e * 600;
    const float* src = tab == 0 ? Wu : (tab == 1 ? Wr : Wf);
    float* dst = tab == 0 ? Tu : (tab == 1 ? Tr : Tf);
    dst[r] = src[(size_t)j * 200 + e];
}

// ---------------------------------------------------------------------------
__global__ __launch_bounds__(256)
void gather_re16(const int* __restrict__ resp, const float* __restrict__ emb,
                 __hip_bfloat16* __restrict__ re16)
{
    int idx = blockIdx.x * 256 + threadIdx.x;
    if (idx < 2560000) {
        int row = idx / 100, q = idx - row * 100;
        float2 v = *(const float2*)(emb + (size_t)resp[row] * 200 + 2 * q);
        ((unsigned*)re16)[idx] = packbf(v.x, v.y);
    }
}

// ---------------------------------------------------------------------------
// Persistent dual-GRU scan: 256 blocks x 1024 thr (16 waves/CU), 50 steps.
// Each of 1000 threads: 1 utt row x 4 cols x 3 gates (float4 W loads; 20
// same-address lanes coalesce). 600 threads: 1 resp row x 2 cols x 3 gates.
// Same f32 accumulation order as the 512-thr version -> identical numerics.
// ---------------------------------------------------------------------------
__global__ __launch_bounds__(1024)
void scan_gru(const int* __restrict__ utt,
              const __hip_bfloat16* __restrict__ EPu,
              const __hip_bfloat16* __restrict__ xpr16,
              const float* __restrict__ WTu, const float* __restrict__ WTr,
              const float* __restrict__ bhu, const float* __restrict__ bhr,
              __hip_bfloat16* __restrict__ ug16,
              __hip_bfloat16* __restrict__ rg16)
{
    const int blk = blockIdx.x;          // 0..255
    const int tid = threadIdx.x;
    const int u0 = blk * 20;
    const int r0 = blk * 2;

    __shared__ float h[22][201];                       // rows 0..19 utt, 20..21 resp
    __shared__ __align__(16) __hip_bfloat16 xpu[20][600];
    __shared__ float xpr_s[2][600];

    for (int i = tid; i < 22 * 201; i += 1024) ((float*)h)[i] = 0.0f;
    __syncthreads();

    const int rg = tid % 20;             // utt row (20 same-jg lanes share W addr)
    const int jg = tid / 20;             // 0..51; active jg<50
    const int j0 = 4 * jg;
    const int brr = tid & 1;             // resp row
    const int bj0 = 2 * (tid >> 1);      // 0..598 for tid<600

    for (int t = 0; t < 50; ++t) {
        // ---- stage x-projections ----
        for (int idx = tid; idx < 1500; idx += 1024) {       // 20 rows x 75 uint4
            int row = idx / 75, q = idx - row * 75;
            int tok = utt[(u0 + row) * 50 + t];
            ((uint4*)&xpu[row][0])[q] = ((const uint4*)(EPu + (size_t)tok * 600))[q];
        }
        for (int idx = tid; idx < 600; idx += 1024) {        // 2 rows x 300 uint
            int row = idx / 300, q = idx - row * 300;
            unsigned p = ((const unsigned*)(xpr16 + (size_t)((r0 + row) * 50 + t) * 600))[q];
            xpr_s[row][2 * q] = bl(p);
            xpr_s[row][2 * q + 1] = bh(p);
        }
        // ---- gh accumulation (reads h) ----
        float aR[4] = {}, aZ[4] = {}, aN[4] = {};
        if (tid < 1000) {
            for (int e = 0; e < 200; e += 4) {
                float4 wrv[4], wzv[4], wnv[4];
#pragma unroll
                for (int u = 0; u < 4; ++u) {
                    const float* w = WTu + (size_t)(e + u) * 600;
                    wrv[u] = *(const float4*)(w + j0);
                    wzv[u] = *(const float4*)(w + 200 + j0);
                    wnv[u] = *(const float4*)(w + 400 + j0);
                }
#pragma unroll
                for (int u = 0; u < 4; ++u) {
                    float h0 = h[rg][e + u];
                    aR[0] = fmaf(h0, wrv[u].x, aR[0]); aR[1] = fmaf(h0, wrv[u].y, aR[1]);
                    aR[2] = fmaf(h0, wrv[u].z, aR[2]); aR[3] = fmaf(h0, wrv[u].w, aR[3]);
                    aZ[0] = fmaf(h0, wzv[u].x, aZ[0]); aZ[1] = fmaf(h0, wzv[u].y, aZ[1]);
                    aZ[2] = fmaf(h0, wzv[u].z, aZ[2]); aZ[3] = fmaf(h0, wzv[u].w, aZ[3]);
                    aN[0] = fmaf(h0, wnv[u].x, aN[0]); aN[1] = fmaf(h0, wnv[u].y, aN[1]);
                    aN[2] = fmaf(h0, wnv[u].z, aN[2]); aN[3] = fmaf(h0, wnv[u].w, aN[3]);
                }
            }
        }
        float bR[2] = {}, bZ[2] = {}, bN[2] = {};
        if (tid < 600) {
            for (int e = 0; e < 200; e += 4) {
                float2 wrv[4], wzv[4], wnv[4];
#pragma unroll
                for (int u = 0; u < 4; ++u) {
                    const float* w = WTr + (size_t)(e + u) * 600;
                    wrv[u] = *(const float2*)(w + bj0);
                    wzv[u] = *(const float2*)(w + 200 + bj0);
                    wnv[u] = *(const float2*)(w + 400 + bj0);
                }
#pragma unroll
                for (int u = 0; u < 4; ++u) {
                    float hv = h[20 + brr][e + u];
                    bR[0] = fmaf(hv, wrv[u].x, bR[0]); bR[1] = fmaf(hv, wrv[u].y, bR[1]);
                    bZ[0] = fmaf(hv, wzv[u].x, bZ[0]); bZ[1] = fmaf(hv, wzv[u].y, bZ[1]);
                    bN[0] = fmaf(hv, wnv[u].x, bN[0]); bN[1] = fmaf(hv, wnv[u].y, bN[1]);
                }
            }
        }
        __syncthreads();
        // ---- epilogue: gates, h update, archives ----
        if (tid < 1000) {
            float hn4[4];
#pragma unroll
            for (int j = 0; j < 4; ++j) {
                const int c = j0 + j;
                float xr = __bfloat162float(xpu[rg][c]);
                float xz = __bfloat162float(xpu[rg][200 + c]);
                float xn = __bfloat162float(xpu[rg][400 + c]);
                float rr = sigm(xr + aR[j] + bhu[c]);
                float zz = sigm(xz + aZ[j] + bhu[200 + c]);
                float nn = tanhfast(xn + rr * (aN[j] + bhu[400 + c]));
                hn4[j] = (1.0f - zz) * nn + zz * h[rg][c];
            }
#pragma unroll
            for (int j = 0; j < 4; ++j) h[rg][j0 + j] = hn4[j];
            uint2 pk;
            pk.x = packbf(hn4[0], hn4[1]);
            pk.y = packbf(hn4[2], hn4[3]);
            *(uint2*)(ug16 + ((size_t)(u0 + rg) * 50 + t) * 200 + j0) = pk;
        }
        if (tid < 600) {
            const int row = 20 + brr;
            const int grow = r0 + brr;
            float hn2[2];
#pragma unroll
            for (int j = 0; j < 2; ++j) {
                const int c = bj0 + j;
                float xr = xpr_s[brr][c];
                float xz = xpr_s[brr][200 + c];
                float xn = xpr_s[brr][400 + c];
                float rr = sigm(xr + bR[j] + bhr[c]);
                float zz = sigm(xz + bZ[j] + bhr[200 + c]);
                float nn = tanhfast(xn + rr * (bN[j] + bhr[400 + c]));
                hn2[j] = (1.0f - zz) * nn + zz * h[row][c];
                h[row][c] = hn2[j];
            }
            *(unsigned*)(rg16 + ((size_t)grow * 50 + t) * 200 + bj0) = packbf(hn2[0], hn2[1]);
        }
        __syncthreads();
    }
}

// ---------------------------------------------------------------------------
// Fused m1/m2 match + conv3x3(2->8)+relu+maxpool3x3 per (b,u).
// ---------------------------------------------------------------------------
__global__ __launch_bounds__(256)
void match_conv_pool(const int* __restrict__ utt, const float* __restrict__ emb,
                     const __hip_bfloat16* __restrict__ ug16,
                     const __hip_bfloat16* __restrict__ re16,
                     const __hip_bfloat16* __restrict__ rgA16,
                     const float* __restrict__ cw, const float* __restrict__ cb,
                     float* __restrict__ pooled)
{
    const int bu = blockIdx.x, b = bu / 10;
    __shared__ __hip_bfloat16 As[50][204];
    __shared__ __hip_bfloat16 Bs[50][204];
    __shared__ float m[2][50][50];
    __shared__ float w[144];
    __shared__ float bsh[8];
    const int tid = threadIdx.x;
    if (tid < 144) w[tid] = cw[tid];
    if (tid >= 144 && tid < 152) bsh[tid - 144] = cb[tid - 144];

    for (int idx = tid; idx < 5000; idx += 256) {
        int l = idx / 100, q = idx - l * 100;
        int tok = utt[bu * 50 + l];
        float2 v = *(const float2*)(emb + (size_t)tok * 200 + 2 * q);
        *(unsigned*)&As[l][2 * q] = packbf(v.x, v.y);
        *(unsigned*)&Bs[l][2 * q] =
            ((const unsigned*)(re16 + (size_t)b * 10000 + (size_t)l * 200))[q];
    }
    __syncthreads();
#pragma unroll 1
    for (int ch = 0; ch < 2; ++ch) {
        for (int task = tid; task < 625; task += 256) {
            int lq = task / 25, tq = task - lq * 25;
            float s00 = 0, s01 = 0, s10 = 0, s11 = 0;
#pragma unroll 4
            for (int q = 0; q < 100; ++q) {
                unsigned a0 = *(const unsigned*)&As[lq][2 * q];
                unsigned a1 = *(const unsigned*)&As[lq + 25][2 * q];
                unsigned b0 = *(const unsigned*)&Bs[tq][2 * q];
                unsigned b1 = *(const unsigned*)&Bs[tq + 25][2 * q];
                float a0l = bl(a0), a0h = bh(a0), a1l = bl(a1), a1h = bh(a1);
                float b0l = bl(b0), b0h = bh(b0), b1l = bl(b1), b1h = bh(b1);
                s00 = fmaf(a0l, b0l, fmaf(a0h, b0h, s00));
                s01 = fmaf(a0l, b1l, fmaf(a0h, b1h, s01));
                s10 = fmaf(a1l, b0l, fmaf(a1h, b0h, s10));
                s11 = fmaf(a1l, b1l, fmaf(a1h, b1h, s11));
            }
            m[ch][lq][tq] = s00;           m[ch][lq][tq + 25] = s01;
            m[ch][lq + 25][tq] = s10;      m[ch][lq + 25][tq + 25] = s11;
        }
        __syncthreads();
        if (ch == 0) {
            for (int idx = tid; idx < 5000; idx += 256) {
                int l = idx / 100, q = idx - l * 100;
                *(unsigned*)&As[l][2 * q] =
                    ((const unsigned*)(ug16 + (size_t)bu * 10000 + (size_t)l * 200))[q];
                *(unsigned*)&Bs[l][2 * q] =
                    ((const unsigned*)(rgA16 + (size_t)b * 10000 + (size_t)l * 200))[q];
            }
            __syncthreads();
        }
    }
#pragma unroll
    for (int k = 0; k < 8; ++k) {
        const int o = tid + k * 256;
        const int c = o >> 8, ph = (o >> 4) & 15, pw = o & 15;
        float mx = -1e30f;
#pragma unroll
        for (int p = 0; p < 3; ++p)
#pragma unroll
            for (int q = 0; q < 3; ++q) {
                const int y = ph * 3 + p, x = pw * 3 + q;
                float s = bsh[c];
#pragma unroll
                for (int ci = 0; ci < 2; ++ci)
#pragma unroll
                    for (int dy = 0; dy < 3; ++dy)
#pragma unroll
                        for (int dx = 0; dx < 3; ++dx)
                            s = fmaf(w[(c * 2 + ci) * 9 + dy * 3 + dx],
                                     m[ci][y + dy][x + dx], s);
                s = fmaxf(s, 0.0f);
                mx = fmaxf(mx, s);
            }
        pooled[(size_t)bu * 2048 + o] = mx;
    }
}

// ---------------------------------------------------------------------------
__global__ __launch_bounds__(256)
void final_gru(const float* __restrict__ xpf, const float* __restrict__ WTf,
               const float* __restrict__ bhf, const float* __restrict__ fw,
               const float* __restrict__ fb, float* __restrict__ out)
{
    const int blk = blockIdx.x;
    const int tid = threadIdx.x;
    __shared__ float h[2][201];
    for (int i = tid; i < 402; i += 256) ((float*)h)[i] = 0.0f;
    __syncthreads();
    const int rr = tid / 100;
    const int j0 = 2 * (tid % 100);
    for (int t = 0; t < 10; ++t) {
        float cR[2] = {}, cZ[2] = {}, cN[2] = {};
        if (tid < 200) {
#pragma unroll 2
            for (int e = 0; e < 200; ++e) {
                const float* w = WTf + (size_t)e * 600;
                float2 wr = *(const float2*)(w + j0);
                float2 wz = *(const float2*)(w + 200 + j0);
                float2 wn = *(const float2*)(w + 400 + j0);
                float hv = h[rr][e];
                cR[0] = fmaf(hv, wr.x, cR[0]); cR[1] = fmaf(hv, wr.y, cR[1]);
                cZ[0] = fmaf(hv, wz.x, cZ[0]); cZ[1] = fmaf(hv, wz.y, cZ[1]);
                cN[0] = fmaf(hv, wn.x, cN[0]); cN[1] = fmaf(hv, wn.y, cN[1]);
            }
        }
        __syncthreads();
        if (tid < 200) {
            const float* xp = xpf + ((size_t)(blk * 2 + rr) * 10 + t) * 600;
#pragma unroll
            for (int j = 0; j < 2; ++j) {
                const int c = j0 + j;
                float rrg = sigm(xp[c] + cR[j] + bhf[c]);
                float zz = sigm(xp[200 + c] + cZ[j] + bhf[200 + c]);
                float nn = tanhfast(xp[400 + c] + rrg * (cN[j] + bhf[400 + c]));
                h[rr][c] = (1.0f - zz) * nn + zz * h[rr][c];
            }
        }
        __syncthreads();
    }
    if (tid < 2) {
        float s = fb[0];
        for (int k = 0; k < 200; ++k) s = fmaf(h[tid][k], fw[k], s);
        out[blk * 2 + tid] = sigm(s);
    }
}

__global__ __launch_bounds__(256)
void fill_out(float* __restrict__ out)
{
    int i = blockIdx.x * 256 + threadIdx.x;
    if (i < 512) out[i] = 0.0f;
}

// ---------------------------------------------------------------------------
extern "C" void kernel_launch(void* const* d_in, const int* in_sizes, int n_in,
                              void* d_out, int out_size, void* d_ws, size_t ws_size,
                              hipStream_t stream)
{
    const int*   utt    = (const int*)d_in[0];
    const int*   resp   = (const int*)d_in[1];
    const float* emb    = (const float*)d_in[2];
    const float* W_ih_u = (const float*)d_in[3];
    const float* W_hh_u = (const float*)d_in[4];
    const float* b_ih_u = (const float*)d_in[5];
    const float* b_hh_u = (const float*)d_in[6];
    const float* W_ih_r = (const float*)d_in[7];
    const float* W_hh_r = (const float*)d_in[8];
    const float* b_ih_r = (const float*)d_in[9];
    const float* b_hh_r = (const float*)d_in[10];
    const float* conv_w = (const float*)d_in[11];
    const float* conv_b = (const float*)d_in[12];
    const float* lin_w  = (const float*)d_in[13];
    const float* lin_b  = (const float*)d_in[14];
    const float* Amat   = (const float*)d_in[15];
    const float* W_ih_f = (const float*)d_in[16];
    const float* W_hh_f = (const float*)d_in[17];
    const float* b_ih_f = (const float*)d_in[18];
    const float* b_hh_f = (const float*)d_in[19];
    const float* flin_w = (const float*)d_in[20];
    const float* flin_b = (const float*)d_in[21];
    float* out = (float*)d_out;
    float* ws  = (float*)d_ws;

    size_t off = 0;
    auto alloc = [&](size_t n) { float* p = ws + off; off += (n + 63) & ~((size_t)63); return p; };
    float* WT_u   = alloc(120000);
    float* WT_r   = alloc(120000);
    float* WT_f   = alloc(120000);
    float* re16f  = alloc(2560000);    // [25600,200] bf16
    float* EPuf   = alloc(15000000);   // [50000,600] bf16; post-scan: pooled
    float* xprf   = alloc(7680000);    // [25600,600] bf16; post-scan: mv/xpf
    float* ug16f  = alloc(25600000);   // [5120,50,200] bf16
    float* rg16f  = alloc(2560000);    // [512,50,200] bf16
    float* rgA16f = alloc(2560000);    // [25600,200] bf16
    // total 56.32M floats = 225 MB

    if (off * sizeof(float) > ws_size) {
        hipLaunchKernelGGL(fill_out, dim3(2), dim3(256), 0, stream, out);
        return;
    }

    __hip_bfloat16* re16  = (__hip_bfloat16*)re16f;
    __hip_bfloat16* EPu   = (__hip_bfloat16*)EPuf;
    __hip_bfloat16* xpr16 = (__hip_bfloat16*)xprf;
    __hip_bfloat16* ug16  = (__hip_bfloat16*)ug16f;
    __hip_bfloat16* rg16  = (__hip_bfloat16*)rg16f;
    __hip_bfloat16* rgA16 = (__hip_bfloat16*)rgA16f;
    float* pooled = EPuf;              // [5120,2048] f32 (EPu dead after scan)
    float* mv     = xprf;              // [5120,50] f32  (xpr dead after scan)
    float* xpf    = xprf + 400000;     // [5120,600] f32

    // 1. weight transposes (f32, for the scan / final GRU)
    hipLaunchKernelGGL(transpose3, dim3(1407), dim3(256), 0, stream,
                       W_hh_u, W_hh_r, W_hh_f, WT_u, WT_r, WT_f);
    // 2. response embedding gather (bf16)
    hipLaunchKernelGGL(gather_re16, dim3(10000), dim3(256), 0, stream, resp, emb, re16);
    // 3. EPu = bf16(emb @ W_ih_u^T + b_ih_u) for the whole vocab  [MFMA]
    hipLaunchKernelGGL(gemm_mfma, dim3(782, 10), dim3(256), 0, stream,
                       (const void*)emb, 0, (const int*)nullptr, W_ih_u, b_ih_u,
                       EPu, 50000, 600);
    // 4. xpr16 = bf16(emb[resp] @ W_ih_r^T + b_ih_r)  [MFMA]
    hipLaunchKernelGGL(gemm_mfma, dim3(400, 10), dim3(256), 0, stream,
                       (const void*)emb, 0, resp, W_ih_r, b_ih_r,
                       xpr16, 25600, 600);
    // 5. persistent dual-GRU scan (1024 thr: 16 waves/CU)
    hipLaunchKernelGGL(scan_gru, dim3(256), dim3(1024), 0, stream,
                       utt, EPu, xpr16, WT_u, WT_r, b_hh_u, b_hh_r, ug16, rg16);
    // 6. rgA16 = bf16(rg @ Amat^T)  [MFMA]
    hipLaunchKernelGGL(gemm_mfma, dim3(400, 4), dim3(256), 0, stream,
                       (const void*)rg16, 1, (const int*)nullptr, Amat,
                       (const float*)nullptr, rgA16, 25600, 200);
    // 7. fused match + conv + pool
    hipLaunchKernelGGL(match_conv_pool, dim3(5120), dim3(256), 0, stream,
                       utt, emb, ug16, re16, rgA16, conv_w, conv_b, pooled);
    // 8. mv = tanh(pooled @ lin_w^T + lin_b)
    hipLaunchKernelGGL(gemm_tn, dim3(80, 1), dim3(256), 0, stream,
                       pooled, 0, (const int*)nullptr, 1, 0, lin_w, lin_b,
                       mv, 0, 5120, 50, 2048, 1);
    // 9. xpf = mv @ W_ih_f^T + b_ih_f
    hipLaunchKernelGGL(gemm_tn, dim3(80, 10), dim3(256), 0, stream,
                       mv, 0, (const int*)nullptr, 1, 0, W_ih_f, b_ih_f,
                       xpf, 0, 5120, 600, 50, 0);
    // 10. final GRU + logit + sigmoid
    hipLaunchKernelGGL(final_gru, dim3(256), dim3(256), 0, stream,
                       xpf, WT_f, b_hh_f, flin_w, flin_b, out);
}

// Round 8
// 1437.988 us; speedup vs baseline: 4.5672x; 4.5672x over previous
//
#include <hip/hip_runtime.h>
#include <hip/hip_bf16.h>

// ---------------------------------------------------------------------------
// SMN forward. B=512 U=10 L=50 E=200 H=200 V=50000
// ---------------------------------------------------------------------------

typedef __attribute__((ext_vector_type(8))) short short8v;   // 8 bf16 (4 VGPR)
typedef __attribute__((ext_vector_type(4))) float f32x4;

__device__ __forceinline__ float sigm(float x) { return 1.0f / (1.0f + __expf(-x)); }
__device__ __forceinline__ float tanhfast(float x) {
    float e = __expf(2.0f * x);
    return 1.0f - 2.0f / (e + 1.0f);
}
__device__ __forceinline__ float bl(unsigned x) { return __uint_as_float(x << 16); }
__device__ __forceinline__ float bh(unsigned x) { return __uint_as_float(x & 0xffff0000u); }
__device__ __forceinline__ unsigned packbf(float a, float b) {
    union { __hip_bfloat16 h[2]; unsigned u; } cv;
    cv.h[0] = __float2bfloat16(a); cv.h[1] = __float2bfloat16(b);
    return cv.u;
}

// ---------------------------------------------------------------------------
// MFMA GEMM: C16[M,N] = bf16(A[M,200] @ W[N,200]^T + bias)
// ---------------------------------------------------------------------------
__global__ __launch_bounds__(256)
void gemm_mfma(const void* __restrict__ Asrc, int a_bf16,
               const int* __restrict__ gidx,
               const float* __restrict__ W, const float* __restrict__ bias,
               __hip_bfloat16* __restrict__ C, int M, int N)
{
    __shared__ __hip_bfloat16 Al[64 * 232];
    __shared__ __hip_bfloat16 Bl[64 * 232];
    const int tid = threadIdx.x;
    const int m0 = blockIdx.x * 64, n0 = blockIdx.y * 64;

    for (int idx = tid; idx < 64 * 29; idx += 256) {
        int r = idx / 29, q = idx - r * 29;
        int k0 = q * 8, row = m0 + r;
        uint4 val = make_uint4(0, 0, 0, 0);
        if (k0 < 200 && row < M) {
            size_t ar = (size_t)(gidx ? gidx[row] : row) * 200 + k0;
            if (a_bf16) {
                val = *(const uint4*)((const __hip_bfloat16*)Asrc + ar);
            } else {
                const float* ap = (const float*)Asrc + ar;
                float4 f0 = *(const float4*)ap;
                float4 f1 = *(const float4*)(ap + 4);
                val.x = packbf(f0.x, f0.y); val.y = packbf(f0.z, f0.w);
                val.z = packbf(f1.x, f1.y); val.w = packbf(f1.z, f1.w);
            }
        }
        *(uint4*)(Al + r * 232 + k0) = val;
    }
    for (int idx = tid; idx < 64 * 29; idx += 256) {
        int r = idx / 29, q = idx - r * 29;
        int k0 = q * 8, row = n0 + r;
        uint4 val = make_uint4(0, 0, 0, 0);
        if (k0 < 200 && row < N) {
            const float* wp = W + (size_t)row * 200 + k0;
            float4 f0 = *(const float4*)wp;
            float4 f1 = *(const float4*)(wp + 4);
            val.x = packbf(f0.x, f0.y); val.y = packbf(f0.z, f0.w);
            val.z = packbf(f1.x, f1.y); val.w = packbf(f1.z, f1.w);
        }
        *(uint4*)(Bl + r * 232 + k0) = val;
    }
    __syncthreads();

    const int wid = tid >> 6, lane = tid & 63;
    const int wm = (wid >> 1) * 32, wn = (wid & 1) * 32;
    const int lrow = lane & 15, lk8 = (lane >> 4) * 8;
    f32x4 acc00 = {0.f, 0.f, 0.f, 0.f}, acc01 = {0.f, 0.f, 0.f, 0.f};
    f32x4 acc10 = {0.f, 0.f, 0.f, 0.f}, acc11 = {0.f, 0.f, 0.f, 0.f};
#pragma unroll
    for (int kk = 0; kk < 7; ++kk) {
        const int kb = kk * 32 + lk8;
        short8v a0 = *(const short8v*)(Al + (wm + lrow) * 232 + kb);
        short8v a1 = *(const short8v*)(Al + (wm + 16 + lrow) * 232 + kb);
        short8v b0 = *(const short8v*)(Bl + (wn + lrow) * 232 + kb);
        short8v b1 = *(const short8v*)(Bl + (wn + 16 + lrow) * 232 + kb);
        acc00 = __builtin_amdgcn_mfma_f32_16x16x32_bf16(a0, b0, acc00, 0, 0, 0);
        acc01 = __builtin_amdgcn_mfma_f32_16x16x32_bf16(a0, b1, acc01, 0, 0, 0);
        acc10 = __builtin_amdgcn_mfma_f32_16x16x32_bf16(a1, b0, acc10, 0, 0, 0);
        acc11 = __builtin_amdgcn_mfma_f32_16x16x32_bf16(a1, b1, acc11, 0, 0, 0);
    }
    const int drow = (lane >> 4) * 4, dcol = lane & 15;
#pragma unroll
    for (int fm = 0; fm < 2; ++fm) {
#pragma unroll
        for (int fn = 0; fn < 2; ++fn) {
            const f32x4 av = (fm == 0) ? (fn == 0 ? acc00 : acc01)
                                       : (fn == 0 ? acc10 : acc11);
            const int gcol = n0 + wn + fn * 16 + dcol;
            if (gcol >= N) continue;
            const float bs = bias ? bias[gcol] : 0.0f;
#pragma unroll
            for (int r = 0; r < 4; ++r) {
                const int grow = m0 + wm + fm * 16 + drow + r;
                if (grow >= M) continue;
                C[(size_t)grow * N + gcol] = __float2bfloat16(av[r] + bs);
            }
        }
    }
}

// ---------------------------------------------------------------------------
// Generic fp32 GEMM (small tails): C = act(A @ W^T + bias)
// ---------------------------------------------------------------------------
__global__ __launch_bounds__(256)
void gemm_tn(const void* __restrict__ Av, int a_bf16,
             const int* __restrict__ gidx, int gstride, int goff,
             const float* __restrict__ W, const float* __restrict__ bias,
             void* __restrict__ Cv, int c_bf16,
             int M, int N, int K, int act)
{
    __shared__ float As[16][64];
    __shared__ float Ws[16][64];
    const int tid = threadIdx.x;
    const int m0 = blockIdx.x * 64;
    const int n0 = blockIdx.y * 64;
    const int lr = tid >> 2;
    const int lk = (tid & 3) << 2;
    const int tx = tid & 15, ty = tid >> 4;

    float acc[4][4];
#pragma unroll
    for (int i = 0; i < 4; ++i)
#pragma unroll
        for (int j = 0; j < 4; ++j) acc[i][j] = 0.0f;

    const int am = m0 + lr;
    size_t arow_off = 0; bool avalid = (am < M);
    if (avalid) arow_off = (size_t)(gidx ? gidx[(size_t)am * gstride + goff] : am) * K;
    const float* arow32 = (const float*)Av + arow_off;
    const __hip_bfloat16* arow16 = (const __hip_bfloat16*)Av + arow_off;
    const int wn = n0 + lr;
    const float* wrow = (wn < N) ? (W + (size_t)wn * K) : nullptr;

    for (int kb = 0; kb < K; kb += 16) {
        const int k = kb + lk;
        float a0 = 0, a1 = 0, a2 = 0, a3 = 0, w0 = 0, w1 = 0, w2 = 0, w3 = 0;
        if (avalid) {
            if (a_bf16) {
                if (k + 3 < K) {
                    uint2 p = *(const uint2*)(arow16 + k);
                    a0 = bl(p.x); a1 = bh(p.x); a2 = bl(p.y); a3 = bh(p.y);
                } else {
                    if (k < K) a0 = __bfloat162float(arow16[k]);
                    if (k + 1 < K) a1 = __bfloat162float(arow16[k + 1]);
                    if (k + 2 < K) a2 = __bfloat162float(arow16[k + 2]);
                }
            } else {
                if (k + 3 < K) { float4 v = *(const float4*)(arow32 + k); a0 = v.x; a1 = v.y; a2 = v.z; a3 = v.w; }
                else { if (k < K) a0 = arow32[k]; if (k + 1 < K) a1 = arow32[k + 1]; if (k + 2 < K) a2 = arow32[k + 2]; }
            }
        }
        if (wrow) {
            if (k + 3 < K) { float4 v = *(const float4*)(wrow + k); w0 = v.x; w1 = v.y; w2 = v.z; w3 = v.w; }
            else { if (k < K) w0 = wrow[k]; if (k + 1 < K) w1 = wrow[k + 1]; if (k + 2 < K) w2 = wrow[k + 2]; }
        }
        __syncthreads();
        As[lk + 0][lr] = a0; As[lk + 1][lr] = a1; As[lk + 2][lr] = a2; As[lk + 3][lr] = a3;
        Ws[lk + 0][lr] = w0; Ws[lk + 1][lr] = w1; Ws[lk + 2][lr] = w2; Ws[lk + 3][lr] = w3;
        __syncthreads();
#pragma unroll
        for (int kk = 0; kk < 16; ++kk) {
            float4 av = *(const float4*)(&As[kk][ty << 2]);
            float4 wv = *(const float4*)(&Ws[kk][tx << 2]);
            float aa[4] = { av.x, av.y, av.z, av.w };
            float ww[4] = { wv.x, wv.y, wv.z, wv.w };
#pragma unroll
            for (int i = 0; i < 4; ++i)
#pragma unroll
                for (int j = 0; j < 4; ++j)
                    acc[i][j] = fmaf(aa[i], ww[j], acc[i][j]);
        }
    }

#pragma unroll
    for (int i = 0; i < 4; ++i) {
        const int row = m0 + (ty << 2) + i;
        if (row >= M) continue;
#pragma unroll
        for (int j = 0; j < 4; ++j) {
            const int col = n0 + (tx << 2) + j;
            if (col >= N) continue;
            float t = acc[i][j];
            if (bias) t += bias[col];
            if (act == 1) t = tanhfast(t);
            if (c_bf16) ((__hip_bfloat16*)Cv)[(size_t)row * N + col] = __float2bfloat16(t);
            else        ((float*)Cv)[(size_t)row * N + col] = t;
        }
    }
}

// ---------------------------------------------------------------------------
__global__ __launch_bounds__(256)
void transpose3(const float* __restrict__ Wu, const float* __restrict__ Wr,
                const float* __restrict__ Wf, float* __restrict__ Tu,
                float* __restrict__ Tr, float* __restrict__ Tf)
{
    int id = blockIdx.x * 256 + threadIdx.x;
    if (id >= 360000) return;
    int tab = id / 120000, r = id - tab * 120000;
    int e = r / 600, j = r - e * 600;
    const float* src = tab == 0 ? Wu : (tab == 1 ? Wr : Wf);
    float* dst = tab == 0 ? Tu : (tab == 1 ? Tr : Tf);
    dst[r] = src[(size_t)j * 200 + e];
}

// ---------------------------------------------------------------------------
// Pack Whh [600][200] f32 -> [608][224] bf16, zero-padded (both GRUs)
// ---------------------------------------------------------------------------
__global__ __launch_bounds__(256)
void pack_whh(const float* __restrict__ Wu, const float* __restrict__ Wr,
              __hip_bfloat16* __restrict__ Du, __hip_bfloat16* __restrict__ Dr)
{
    int idx = blockIdx.x * 256 + threadIdx.x;     // 608*224 = 136192
    if (idx >= 136192) return;
    int j = idx / 224, e = idx - j * 224;
    bool v = (j < 600) && (e < 200);
    Du[idx] = __float2bfloat16(v ? Wu[(size_t)j * 200 + e] : 0.0f);
    Dr[idx] = __float2bfloat16(v ? Wr[(size_t)j * 200 + e] : 0.0f);
}

// ---------------------------------------------------------------------------
__global__ __launch_bounds__(256)
void gather_re16(const int* __restrict__ resp, const float* __restrict__ emb,
                 __hip_bfloat16* __restrict__ re16)
{
    int idx = blockIdx.x * 256 + threadIdx.x;
    if (idx < 2560000) {
        int row = idx / 100, q = idx - row * 100;
        float2 v = *(const float2*)(emb + (size_t)resp[row] * 200 + 2 * q);
        ((unsigned*)re16)[idx] = packbf(v.x, v.y);
    }
}

// ---------------------------------------------------------------------------
// MFMA persistent GRU scan. 176 blocks x 512 thr (8 waves), 50 steps.
// Blocks 0..159: utterance rows (32 each, 5120). Blocks 160..175: response
// rows (32 each, 512). Per step: gh = bf16(h) @ W^T via mfma_16x16x32_bf16
// (f32 accum), then exact-f32 gate blend; h16 feeds the next step's A-frags.
// W tables are bf16 [608][224] zero-padded, L2-resident, streamed per step.
// ---------------------------------------------------------------------------
__global__ __launch_bounds__(512)
void scan_gru_mfma(const int* __restrict__ utt,
                   const __hip_bfloat16* __restrict__ EPu,
                   const __hip_bfloat16* __restrict__ xpr16,
                   const __hip_bfloat16* __restrict__ Wu16,
                   const __hip_bfloat16* __restrict__ Wr16,
                   const float* __restrict__ bhu, const float* __restrict__ bhr,
                   __hip_bfloat16* __restrict__ ug16,
                   __hip_bfloat16* __restrict__ rg16)
{
    __shared__ __align__(16) float gh[32][612];            // 78336 B (612%32=4 -> 2-way)
    __shared__ __align__(16) float hf[32][204];            // 26112 B exact f32 state
    __shared__ __align__(16) __hip_bfloat16 h16[32][232];  // 14848 B MFMA A operand

    const int tid = threadIdx.x;
    const bool isResp = (int)blockIdx.x >= 160;
    const int row0 = isResp ? ((int)blockIdx.x - 160) * 32 : (int)blockIdx.x * 32;
    const __hip_bfloat16* Wt = isResp ? Wr16 : Wu16;
    const float* bgate = isResp ? bhr : bhu;
    __hip_bfloat16* arch = isResp ? rg16 : ug16;

    for (int i = tid; i < 32 * 204; i += 512) ((float*)hf)[i] = 0.0f;
    for (int i = tid; i < 928; i += 512) ((uint4*)h16)[i] = make_uint4(0, 0, 0, 0);
    __syncthreads();

    const int wid = tid >> 6, lane = tid & 63;
    const int ntBase = (wid < 6) ? wid * 5 : 30 + (wid - 6) * 4;
    const int ntCnt  = (wid < 6) ? 5 : 4;
    const int lrow = lane & 15, lk8 = (lane >> 4) * 8;
    const int drow = (lane >> 4) * 4, dcol = lane & 15;

    for (int t = 0; t < 50; ++t) {
        // ---- MFMA phase: gh = h16 @ Wt^T ----
        f32x4 a0[5], a1[5];
#pragma unroll
        for (int i = 0; i < 5; ++i) {
            a0[i] = (f32x4){0.f, 0.f, 0.f, 0.f};
            a1[i] = (f32x4){0.f, 0.f, 0.f, 0.f};
        }
#pragma unroll
        for (int kk = 0; kk < 7; ++kk) {
            short8v A0 = *(const short8v*)(&h16[lrow][kk * 32 + lk8]);
            short8v A1 = *(const short8v*)(&h16[16 + lrow][kk * 32 + lk8]);
#pragma unroll
            for (int i = 0; i < 5; ++i) {
                if (i < ntCnt) {
                    const int j = (ntBase + i) * 16 + lrow;
                    short8v B = *(const short8v*)(Wt + (size_t)j * 224 + kk * 32 + lk8);
                    a0[i] = __builtin_amdgcn_mfma_f32_16x16x32_bf16(A0, B, a0[i], 0, 0, 0);
                    a1[i] = __builtin_amdgcn_mfma_f32_16x16x32_bf16(A1, B, a1[i], 0, 0, 0);
                }
            }
        }
#pragma unroll
        for (int i = 0; i < 5; ++i) {
            if (i < ntCnt) {
                const int j = (ntBase + i) * 16 + dcol;
#pragma unroll
                for (int r = 0; r < 4; ++r) {
                    gh[drow + r][j] = a0[i][r];
                    gh[16 + drow + r][j] = a1[i][r];
                }
            }
        }
        __syncthreads();
        // ---- gate phase: 32 rows x 25 col-groups of 8 = 800 tasks ----
        for (int task = tid; task < 800; task += 512) {
            const int row = task / 25;
            const int c0 = (task - row * 25) * 8;
            const int grow = row0 + row;
            const __hip_bfloat16* xp = isResp
                ? (xpr16 + ((size_t)grow * 50 + t) * 600)
                : (EPu + (size_t)utt[grow * 50 + t] * 600);
            uint4 xrv = *(const uint4*)(xp + c0);
            uint4 xzv = *(const uint4*)(xp + 200 + c0);
            uint4 xnv = *(const uint4*)(xp + 400 + c0);
            const unsigned xra[4] = { xrv.x, xrv.y, xrv.z, xrv.w };
            const unsigned xza[4] = { xzv.x, xzv.y, xzv.z, xzv.w };
            const unsigned xna[4] = { xnv.x, xnv.y, xnv.z, xnv.w };
            float hn[8];
#pragma unroll
            for (int j = 0; j < 8; ++j) {
                const int c = c0 + j;
                const float xr = (j & 1) ? bh(xra[j >> 1]) : bl(xra[j >> 1]);
                const float xz = (j & 1) ? bh(xza[j >> 1]) : bl(xza[j >> 1]);
                const float xn = (j & 1) ? bh(xna[j >> 1]) : bl(xna[j >> 1]);
                const float rr = sigm(xr + gh[row][c] + bgate[c]);
                const float zz = sigm(xz + gh[row][200 + c] + bgate[200 + c]);
                const float nn = tanhfast(xn + rr * (gh[row][400 + c] + bgate[400 + c]));
                hn[j] = (1.0f - zz) * nn + zz * hf[row][c];
            }
            *(float4*)(&hf[row][c0])     = (float4){hn[0], hn[1], hn[2], hn[3]};
            *(float4*)(&hf[row][c0 + 4]) = (float4){hn[4], hn[5], hn[6], hn[7]};
            uint4 pk;
            pk.x = packbf(hn[0], hn[1]); pk.y = packbf(hn[2], hn[3]);
            pk.z = packbf(hn[4], hn[5]); pk.w = packbf(hn[6], hn[7]);
            *(uint4*)(&h16[row][c0]) = pk;
            *(uint4*)(arch + ((size_t)grow * 50 + t) * 200 + c0) = pk;
        }
        __syncthreads();
    }
}

// ---------------------------------------------------------------------------
// Fused m1/m2 match + conv3x3(2->8)+relu+maxpool3x3 per (b,u).
// ---------------------------------------------------------------------------
__global__ __launch_bounds__(256)
void match_conv_pool(const int* __restrict__ utt, const float* __restrict__ emb,
                     const __hip_bfloat16* __restrict__ ug16,
                     const __hip_bfloat16* __restrict__ re16,
                     const __hip_bfloat16* __restrict__ rgA16,
                     const float* __restrict__ cw, const float* __restrict__ cb,
                     float* __restrict__ pooled)
{
    const int bu = blockIdx.x, b = bu / 10;
    __shared__ __hip_bfloat16 As[50][204];
    __shared__ __hip_bfloat16 Bs[50][204];
    __shared__ float m[2][50][50];
    __shared__ float w[144];
    __shared__ float bsh[8];
    const int tid = threadIdx.x;
    if (tid < 144) w[tid] = cw[tid];
    if (tid >= 144 && tid < 152) bsh[tid - 144] = cb[tid - 144];

    for (int idx = tid; idx < 5000; idx += 256) {
        int l = idx / 100, q = idx - l * 100;
        int tok = utt[bu * 50 + l];
        float2 v = *(const float2*)(emb + (size_t)tok * 200 + 2 * q);
        *(unsigned*)&As[l][2 * q] = packbf(v.x, v.y);
        *(unsigned*)&Bs[l][2 * q] =
            ((const unsigned*)(re16 + (size_t)b * 10000 + (size_t)l * 200))[q];
    }
    __syncthreads();
#pragma unroll 1
    for (int ch = 0; ch < 2; ++ch) {
        for (int task = tid; task < 625; task += 256) {
            int lq = task / 25, tq = task - lq * 25;
            float s00 = 0, s01 = 0, s10 = 0, s11 = 0;
#pragma unroll 4
            for (int q = 0; q < 100; ++q) {
                unsigned a0 = *(const unsigned*)&As[lq][2 * q];
                unsigned a1 = *(const unsigned*)&As[lq + 25][2 * q];
                unsigned b0 = *(const unsigned*)&Bs[tq][2 * q];
                unsigned b1 = *(const unsigned*)&Bs[tq + 25][2 * q];
                float a0l = bl(a0), a0h = bh(a0), a1l = bl(a1), a1h = bh(a1);
                float b0l = bl(b0), b0h = bh(b0), b1l = bl(b1), b1h = bh(b1);
                s00 = fmaf(a0l, b0l, fmaf(a0h, b0h, s00));
                s01 = fmaf(a0l, b1l, fmaf(a0h, b1h, s01));
                s10 = fmaf(a1l, b0l, fmaf(a1h, b0h, s10));
                s11 = fmaf(a1l, b1l, fmaf(a1h, b1h, s11));
            }
            m[ch][lq][tq] = s00;           m[ch][lq][tq + 25] = s01;
            m[ch][lq + 25][tq] = s10;      m[ch][lq + 25][tq + 25] = s11;
        }
        __syncthreads();
        if (ch == 0) {
            for (int idx = tid; idx < 5000; idx += 256) {
                int l = idx / 100, q = idx - l * 100;
                *(unsigned*)&As[l][2 * q] =
                    ((const unsigned*)(ug16 + (size_t)bu * 10000 + (size_t)l * 200))[q];
                *(unsigned*)&Bs[l][2 * q] =
                    ((const unsigned*)(rgA16 + (size_t)b * 10000 + (size_t)l * 200))[q];
            }
            __syncthreads();
        }
    }
#pragma unroll
    for (int k = 0; k < 8; ++k) {
        const int o = tid + k * 256;
        const int c = o >> 8, ph = (o >> 4) & 15, pw = o & 15;
        float mx = -1e30f;
#pragma unroll
        for (int p = 0; p < 3; ++p)
#pragma unroll
            for (int q = 0; q < 3; ++q) {
                const int y = ph * 3 + p, x = pw * 3 + q;
                float s = bsh[c];
#pragma unroll
                for (int ci = 0; ci < 2; ++ci)
#pragma unroll
                    for (int dy = 0; dy < 3; ++dy)
#pragma unroll
                        for (int dx = 0; dx < 3; ++dx)
                            s = fmaf(w[(c * 2 + ci) * 9 + dy * 3 + dx],
                                     m[ci][y + dy][x + dx], s);
                s = fmaxf(s, 0.0f);
                mx = fmaxf(mx, s);
            }
        pooled[(size_t)bu * 2048 + o] = mx;
    }
}

// ---------------------------------------------------------------------------
__global__ __launch_bounds__(256)
void final_gru(const float* __restrict__ xpf, const float* __restrict__ WTf,
               const float* __restrict__ bhf, const float* __restrict__ fw,
               const float* __restrict__ fb, float* __restrict__ out)
{
    const int blk = blockIdx.x;
    const int tid = threadIdx.x;
    __shared__ float h[2][201];
    for (int i = tid; i < 402; i += 256) ((float*)h)[i] = 0.0f;
    __syncthreads();
    const int rr = tid / 100;
    const int j0 = 2 * (tid % 100);
    for (int t = 0; t < 10; ++t) {
        float cR[2] = {}, cZ[2] = {}, cN[2] = {};
        if (tid < 200) {
#pragma unroll 2
            for (int e = 0; e < 200; ++e) {
                const float* w = WTf + (size_t)e * 600;
                float2 wr = *(const float2*)(w + j0);
                float2 wz = *(const float2*)(w + 200 + j0);
                float2 wn = *(const float2*)(w + 400 + j0);
                float hv = h[rr][e];
                cR[0] = fmaf(hv, wr.x, cR[0]); cR[1] = fmaf(hv, wr.y, cR[1]);
                cZ[0] = fmaf(hv, wz.x, cZ[0]); cZ[1] = fmaf(hv, wz.y, cZ[1]);
                cN[0] = fmaf(hv, wn.x, cN[0]); cN[1] = fmaf(hv, wn.y, cN[1]);
            }
        }
        __syncthreads();
        if (tid < 200) {
            const float* xp = xpf + ((size_t)(blk * 2 + rr) * 10 + t) * 600;
#pragma unroll
            for (int j = 0; j < 2; ++j) {
                const int c = j0 + j;
                float rrg = sigm(xp[c] + cR[j] + bhf[c]);
                float zz = sigm(xp[200 + c] + cZ[j] + bhf[200 + c]);
                float nn = tanhfast(xp[400 + c] + rrg * (cN[j] + bhf[400 + c]));
                h[rr][c] = (1.0f - zz) * nn + zz * h[rr][c];
            }
        }
        __syncthreads();
    }
    if (tid < 2) {
        float s = fb[0];
        for (int k = 0; k < 200; ++k) s = fmaf(h[tid][k], fw[k], s);
        out[blk * 2 + tid] = sigm(s);
    }
}

__global__ __launch_bounds__(256)
void fill_out(float* __restrict__ out)
{
    int i = blockIdx.x * 256 + threadIdx.x;
    if (i < 512) out[i] = 0.0f;
}

// ---------------------------------------------------------------------------
extern "C" void kernel_launch(void* const* d_in, const int* in_sizes, int n_in,
                              void* d_out, int out_size, void* d_ws, size_t ws_size,
                              hipStream_t stream)
{
    const int*   utt    = (const int*)d_in[0];
    const int*   resp   = (const int*)d_in[1];
    const float* emb    = (const float*)d_in[2];
    const float* W_ih_u = (const float*)d_in[3];
    const float* W_hh_u = (const float*)d_in[4];
    const float* b_ih_u = (const float*)d_in[5];
    const float* b_hh_u = (const float*)d_in[6];
    const float* W_ih_r = (const float*)d_in[7];
    const float* W_hh_r = (const float*)d_in[8];
    const float* b_ih_r = (const float*)d_in[9];
    const float* b_hh_r = (const float*)d_in[10];
    const float* conv_w = (const float*)d_in[11];
    const float* conv_b = (const float*)d_in[12];
    const float* lin_w  = (const float*)d_in[13];
    const float* lin_b  = (const float*)d_in[14];
    const float* Amat   = (const float*)d_in[15];
    const float* W_ih_f = (const float*)d_in[16];
    const float* W_hh_f = (const float*)d_in[17];
    const float* b_ih_f = (const float*)d_in[18];
    const float* b_hh_f = (const float*)d_in[19];
    const float* flin_w = (const float*)d_in[20];
    const float* flin_b = (const float*)d_in[21];
    float* out = (float*)d_out;
    float* ws  = (float*)d_ws;

    size_t off = 0;
    auto alloc = [&](size_t n) { float* p = ws + off; off += (n + 63) & ~((size_t)63); return p; };
    float* WT_u   = alloc(120000);
    float* WT_r   = alloc(120000);
    float* WT_f   = alloc(120000);
    float* Wu16f  = alloc(68096);      // [608,224] bf16
    float* Wr16f  = alloc(68096);      // [608,224] bf16
    float* re16f  = alloc(2560000);    // [25600,200] bf16
    float* EPuf   = alloc(15000000);   // [50000,600] bf16; post-scan: pooled
    float* xprf   = alloc(7680000);    // [25600,600] bf16; post-scan: mv/xpf
    float* ug16f  = alloc(25600000);   // [5120,50,200] bf16
    float* rg16f  = alloc(2560000);    // [512,50,200] bf16
    float* rgA16f = alloc(2560000);    // [25600,200] bf16
    // total ~56.5M floats = 226 MB

    if (off * sizeof(float) > ws_size) {
        hipLaunchKernelGGL(fill_out, dim3(2), dim3(256), 0, stream, out);
        return;
    }

    __hip_bfloat16* Wu16  = (__hip_bfloat16*)Wu16f;
    __hip_bfloat16* Wr16  = (__hip_bfloat16*)Wr16f;
    __hip_bfloat16* re16  = (__hip_bfloat16*)re16f;
    __hip_bfloat16* EPu   = (__hip_bfloat16*)EPuf;
    __hip_bfloat16* xpr16 = (__hip_bfloat16*)xprf;
    __hip_bfloat16* ug16  = (__hip_bfloat16*)ug16f;
    __hip_bfloat16* rg16  = (__hip_bfloat16*)rg16f;
    __hip_bfloat16* rgA16 = (__hip_bfloat16*)rgA16f;
    float* pooled = EPuf;              // [5120,2048] f32 (EPu dead after scan)
    float* mv     = xprf;              // [5120,50] f32  (xpr dead after scan)
    float* xpf    = xprf + 400000;     // [5120,600] f32

    // 1. weight transposes (WT_f used by final_gru)
    hipLaunchKernelGGL(transpose3, dim3(1407), dim3(256), 0, stream,
                       W_hh_u, W_hh_r, W_hh_f, WT_u, WT_r, WT_f);
    // 1b. pack recurrent weights bf16 padded for the MFMA scan
    hipLaunchKernelGGL(pack_whh, dim3(532), dim3(256), 0, stream,
                       W_hh_u, W_hh_r, Wu16, Wr16);
    // 2. response embedding gather (bf16)
    hipLaunchKernelGGL(gather_re16, dim3(10000), dim3(256), 0, stream, resp, emb, re16);
    // 3. EPu = bf16(emb @ W_ih_u^T + b_ih_u) for the whole vocab  [MFMA]
    hipLaunchKernelGGL(gemm_mfma, dim3(782, 10), dim3(256), 0, stream,
                       (const void*)emb, 0, (const int*)nullptr, W_ih_u, b_ih_u,
                       EPu, 50000, 600);
    // 4. xpr16 = bf16(emb[resp] @ W_ih_r^T + b_ih_r)  [MFMA]
    hipLaunchKernelGGL(gemm_mfma, dim3(400, 10), dim3(256), 0, stream,
                       (const void*)emb, 0, resp, W_ih_r, b_ih_r,
                       xpr16, 25600, 600);
    // 5. persistent MFMA dual-GRU scan: 160 utt blocks + 16 resp blocks
    hipLaunchKernelGGL(scan_gru_mfma, dim3(176), dim3(512), 0, stream,
                       utt, EPu, xpr16, Wu16, Wr16, b_hh_u, b_hh_r, ug16, rg16);
    // 6. rgA16 = bf16(rg @ Amat^T)  [MFMA]
    hipLaunchKernelGGL(gemm_mfma, dim3(400, 4), dim3(256), 0, stream,
                       (const void*)rg16, 1, (const int*)nullptr, Amat,
                       (const float*)nullptr, rgA16, 25600, 200);
    // 7. fused match + conv + pool
    hipLaunchKernelGGL(match_conv_pool, dim3(5120), dim3(256), 0, stream,
                       utt, emb, ug16, re16, rgA16, conv_w, conv_b, pooled);
    // 8. mv = tanh(pooled @ lin_w^T + lin_b)
    hipLaunchKernelGGL(gemm_tn, dim3(80, 1), dim3(256), 0, stream,
                       pooled, 0, (const int*)nullptr, 1, 0, lin_w, lin_b,
                       mv, 0, 5120, 50, 2048, 1);
    // 9. xpf = mv @ W_ih_f^T + b_ih_f
    hipLaunchKernelGGL(gemm_tn, dim3(80, 10), dim3(256), 0, stream,
                       mv, 0, (const int*)nullptr, 1, 0, W_ih_f, b_ih_f,
                       xpf, 0, 5120, 600, 50, 0);
    // 10. final GRU + logit + sigmoid
    hipLaunchKernelGGL(final_gru, dim3(256), dim3(256), 0, stream,
                       xpf, WT_f, b_hh_f, flin_w, flin_b, out);
}

// Round 9
// 1172.477 us; speedup vs baseline: 5.6014x; 1.2265x over previous
//
#include <hip/hip_runtime.h>
#include <hip/hip_bf16.h>

// ---------------------------------------------------------------------------
// SMN forward. B=512 U=10 L=50 E=200 H=200 V=50000
// ---------------------------------------------------------------------------

typedef __attribute__((ext_vector_type(8))) short short8v;   // 8 bf16 (4 VGPR)
typedef __attribute__((ext_vector_type(4))) float f32x4;

__device__ __forceinline__ float sigm(float x) { return 1.0f / (1.0f + __expf(-x)); }
__device__ __forceinline__ float tanhfast(float x) {
    float e = __expf(2.0f * x);
    return 1.0f - 2.0f / (e + 1.0f);
}
__device__ __forceinline__ float bl(unsigned x) { return __uint_as_float(x << 16); }
__device__ __forceinline__ float bh(unsigned x) { return __uint_as_float(x & 0xffff0000u); }
__device__ __forceinline__ unsigned packbf(float a, float b) {
    union { __hip_bfloat16 h[2]; unsigned u; } cv;
    cv.h[0] = __float2bfloat16(a); cv.h[1] = __float2bfloat16(b);
    return cv.u;
}

// ---------------------------------------------------------------------------
// MFMA GEMM: C16[M,N] = bf16(A[M,200] @ W[N,200]^T + bias)
// ---------------------------------------------------------------------------
__global__ __launch_bounds__(256)
void gemm_mfma(const void* __restrict__ Asrc, int a_bf16,
               const int* __restrict__ gidx,
               const float* __restrict__ W, const float* __restrict__ bias,
               __hip_bfloat16* __restrict__ C, int M, int N)
{
    __shared__ __hip_bfloat16 Al[64 * 232];
    __shared__ __hip_bfloat16 Bl[64 * 232];
    const int tid = threadIdx.x;
    const int m0 = blockIdx.x * 64, n0 = blockIdx.y * 64;

    for (int idx = tid; idx < 64 * 29; idx += 256) {
        int r = idx / 29, q = idx - r * 29;
        int k0 = q * 8, row = m0 + r;
        uint4 val = make_uint4(0, 0, 0, 0);
        if (k0 < 200 && row < M) {
            size_t ar = (size_t)(gidx ? gidx[row] : row) * 200 + k0;
            if (a_bf16) {
                val = *(const uint4*)((const __hip_bfloat16*)Asrc + ar);
            } else {
                const float* ap = (const float*)Asrc + ar;
                float4 f0 = *(const float4*)ap;
                float4 f1 = *(const float4*)(ap + 4);
                val.x = packbf(f0.x, f0.y); val.y = packbf(f0.z, f0.w);
                val.z = packbf(f1.x, f1.y); val.w = packbf(f1.z, f1.w);
            }
        }
        *(uint4*)(Al + r * 232 + k0) = val;
    }
    for (int idx = tid; idx < 64 * 29; idx += 256) {
        int r = idx / 29, q = idx - r * 29;
        int k0 = q * 8, row = n0 + r;
        uint4 val = make_uint4(0, 0, 0, 0);
        if (k0 < 200 && row < N) {
            const float* wp = W + (size_t)row * 200 + k0;
            float4 f0 = *(const float4*)wp;
            float4 f1 = *(const float4*)(wp + 4);
            val.x = packbf(f0.x, f0.y); val.y = packbf(f0.z, f0.w);
            val.z = packbf(f1.x, f1.y); val.w = packbf(f1.z, f1.w);
        }
        *(uint4*)(Bl + r * 232 + k0) = val;
    }
    __syncthreads();

    const int wid = tid >> 6, lane = tid & 63;
    const int wm = (wid >> 1) * 32, wn = (wid & 1) * 32;
    const int lrow = lane & 15, lk8 = (lane >> 4) * 8;
    f32x4 acc00 = {0.f, 0.f, 0.f, 0.f}, acc01 = {0.f, 0.f, 0.f, 0.f};
    f32x4 acc10 = {0.f, 0.f, 0.f, 0.f}, acc11 = {0.f, 0.f, 0.f, 0.f};
#pragma unroll
    for (int kk = 0; kk < 7; ++kk) {
        const int kb = kk * 32 + lk8;
        short8v a0 = *(const short8v*)(Al + (wm + lrow) * 232 + kb);
        short8v a1 = *(const short8v*)(Al + (wm + 16 + lrow) * 232 + kb);
        short8v b0 = *(const short8v*)(Bl + (wn + lrow) * 232 + kb);
        short8v b1 = *(const short8v*)(Bl + (wn + 16 + lrow) * 232 + kb);
        acc00 = __builtin_amdgcn_mfma_f32_16x16x32_bf16(a0, b0, acc00, 0, 0, 0);
        acc01 = __builtin_amdgcn_mfma_f32_16x16x32_bf16(a0, b1, acc01, 0, 0, 0);
        acc10 = __builtin_amdgcn_mfma_f32_16x16x32_bf16(a1, b0, acc10, 0, 0, 0);
        acc11 = __builtin_amdgcn_mfma_f32_16x16x32_bf16(a1, b1, acc11, 0, 0, 0);
    }
    const int drow = (lane >> 4) * 4, dcol = lane & 15;
#pragma unroll
    for (int fm = 0; fm < 2; ++fm) {
#pragma unroll
        for (int fn = 0; fn < 2; ++fn) {
            const f32x4 av = (fm == 0) ? (fn == 0 ? acc00 : acc01)
                                       : (fn == 0 ? acc10 : acc11);
            const int gcol = n0 + wn + fn * 16 + dcol;
            if (gcol >= N) continue;
            const float bs = bias ? bias[gcol] : 0.0f;
#pragma unroll
            for (int r = 0; r < 4; ++r) {
                const int grow = m0 + wm + fm * 16 + drow + r;
                if (grow >= M) continue;
                C[(size_t)grow * N + gcol] = __float2bfloat16(av[r] + bs);
            }
        }
    }
}

// ---------------------------------------------------------------------------
// Generic fp32 GEMM (small tails): C = act(A @ W^T + bias)
// ---------------------------------------------------------------------------
__global__ __launch_bounds__(256)
void gemm_tn(const void* __restrict__ Av, int a_bf16,
             const int* __restrict__ gidx, int gstride, int goff,
             const float* __restrict__ W, const float* __restrict__ bias,
             void* __restrict__ Cv, int c_bf16,
             int M, int N, int K, int act)
{
    __shared__ float As[16][64];
    __shared__ float Ws[16][64];
    const int tid = threadIdx.x;
    const int m0 = blockIdx.x * 64;
    const int n0 = blockIdx.y * 64;
    const int lr = tid >> 2;
    const int lk = (tid & 3) << 2;
    const int tx = tid & 15, ty = tid >> 4;

    float acc[4][4];
#pragma unroll
    for (int i = 0; i < 4; ++i)
#pragma unroll
        for (int j = 0; j < 4; ++j) acc[i][j] = 0.0f;

    const int am = m0 + lr;
    size_t arow_off = 0; bool avalid = (am < M);
    if (avalid) arow_off = (size_t)(gidx ? gidx[(size_t)am * gstride + goff] : am) * K;
    const float* arow32 = (const float*)Av + arow_off;
    const __hip_bfloat16* arow16 = (const __hip_bfloat16*)Av + arow_off;
    const int wn = n0 + lr;
    const float* wrow = (wn < N) ? (W + (size_t)wn * K) : nullptr;

    for (int kb = 0; kb < K; kb += 16) {
        const int k = kb + lk;
        float a0 = 0, a1 = 0, a2 = 0, a3 = 0, w0 = 0, w1 = 0, w2 = 0, w3 = 0;
        if (avalid) {
            if (a_bf16) {
                if (k + 3 < K) {
                    uint2 p = *(const uint2*)(arow16 + k);
                    a0 = bl(p.x); a1 = bh(p.x); a2 = bl(p.y); a3 = bh(p.y);
                } else {
                    if (k < K) a0 = __bfloat162float(arow16[k]);
                    if (k + 1 < K) a1 = __bfloat162float(arow16[k + 1]);
                    if (k + 2 < K) a2 = __bfloat162float(arow16[k + 2]);
                }
            } else {
                if (k + 3 < K) { float4 v = *(const float4*)(arow32 + k); a0 = v.x; a1 = v.y; a2 = v.z; a3 = v.w; }
                else { if (k < K) a0 = arow32[k]; if (k + 1 < K) a1 = arow32[k + 1]; if (k + 2 < K) a2 = arow32[k + 2]; }
            }
        }
        if (wrow) {
            if (k + 3 < K) { float4 v = *(const float4*)(wrow + k); w0 = v.x; w1 = v.y; w2 = v.z; w3 = v.w; }
            else { if (k < K) w0 = wrow[k]; if (k + 1 < K) w1 = wrow[k + 1]; if (k + 2 < K) w2 = wrow[k + 2]; }
        }
        __syncthreads();
        As[lk + 0][lr] = a0; As[lk + 1][lr] = a1; As[lk + 2][lr] = a2; As[lk + 3][lr] = a3;
        Ws[lk + 0][lr] = w0; Ws[lk + 1][lr] = w1; Ws[lk + 2][lr] = w2; Ws[lk + 3][lr] = w3;
        __syncthreads();
#pragma unroll
        for (int kk = 0; kk < 16; ++kk) {
            float4 av = *(const float4*)(&As[kk][ty << 2]);
            float4 wv = *(const float4*)(&Ws[kk][tx << 2]);
            float aa[4] = { av.x, av.y, av.z, av.w };
            float ww[4] = { wv.x, wv.y, wv.z, wv.w };
#pragma unroll
            for (int i = 0; i < 4; ++i)
#pragma unroll
                for (int j = 0; j < 4; ++j)
                    acc[i][j] = fmaf(aa[i], ww[j], acc[i][j]);
        }
    }

#pragma unroll
    for (int i = 0; i < 4; ++i) {
        const int row = m0 + (ty << 2) + i;
        if (row >= M) continue;
#pragma unroll
        for (int j = 0; j < 4; ++j) {
            const int col = n0 + (tx << 2) + j;
            if (col >= N) continue;
            float t = acc[i][j];
            if (bias) t += bias[col];
            if (act == 1) t = tanhfast(t);
            if (c_bf16) ((__hip_bfloat16*)Cv)[(size_t)row * N + col] = __float2bfloat16(t);
            else        ((float*)Cv)[(size_t)row * N + col] = t;
        }
    }
}

// ---------------------------------------------------------------------------
// WT_f[200][600] = W_hh_f[600][200]^T  (final GRU only)
// ---------------------------------------------------------------------------
__global__ __launch_bounds__(256)
void transpose_wf(const float* __restrict__ Wf, float* __restrict__ Tf)
{
    int id = blockIdx.x * 256 + threadIdx.x;
    if (id < 120000) {
        int e = id / 600, j = id - e * 600;
        Tf[id] = Wf[(size_t)j * 200 + e];
    }
}

// ---------------------------------------------------------------------------
// Pack Whh [600][200] f32 -> [608][224] bf16, zero-padded (both GRUs)
// ---------------------------------------------------------------------------
__global__ __launch_bounds__(256)
void pack_whh(const float* __restrict__ Wu, const float* __restrict__ Wr,
              __hip_bfloat16* __restrict__ Du, __hip_bfloat16* __restrict__ Dr)
{
    int idx = blockIdx.x * 256 + threadIdx.x;     // 608*224 = 136192
    if (idx >= 136192) return;
    int j = idx / 224, e = idx - j * 224;
    bool v = (j < 600) && (e < 200);
    Du[idx] = __float2bfloat16(v ? Wu[(size_t)j * 200 + e] : 0.0f);
    Dr[idx] = __float2bfloat16(v ? Wr[(size_t)j * 200 + e] : 0.0f);
}

// ---------------------------------------------------------------------------
__global__ __launch_bounds__(256)
void gather_re16(const int* __restrict__ resp, const float* __restrict__ emb,
                 __hip_bfloat16* __restrict__ re16)
{
    int idx = blockIdx.x * 256 + threadIdx.x;
    if (idx < 2560000) {
        int row = idx / 100, q = idx - row * 100;
        float2 v = *(const float2*)(emb + (size_t)resp[row] * 200 + 2 * q);
        ((unsigned*)re16)[idx] = packbf(v.x, v.y);
    }
}

// ---------------------------------------------------------------------------
// MFMA persistent GRU scan. 176 blocks x 512 thr (8 waves), 50 steps.
// ---------------------------------------------------------------------------
__global__ __launch_bounds__(512)
void scan_gru_mfma(const int* __restrict__ utt,
                   const __hip_bfloat16* __restrict__ EPu,
                   const __hip_bfloat16* __restrict__ xpr16,
                   const __hip_bfloat16* __restrict__ Wu16,
                   const __hip_bfloat16* __restrict__ Wr16,
                   const float* __restrict__ bhu, const float* __restrict__ bhr,
                   __hip_bfloat16* __restrict__ ug16,
                   __hip_bfloat16* __restrict__ rg16)
{
    __shared__ __align__(16) float gh[32][612];
    __shared__ __align__(16) float hf[32][204];
    __shared__ __align__(16) __hip_bfloat16 h16[32][232];

    const int tid = threadIdx.x;
    const bool isResp = (int)blockIdx.x >= 160;
    const int row0 = isResp ? ((int)blockIdx.x - 160) * 32 : (int)blockIdx.x * 32;
    const __hip_bfloat16* Wt = isResp ? Wr16 : Wu16;
    const float* bgate = isResp ? bhr : bhu;
    __hip_bfloat16* arch = isResp ? rg16 : ug16;

    for (int i = tid; i < 32 * 204; i += 512) ((float*)hf)[i] = 0.0f;
    for (int i = tid; i < 928; i += 512) ((uint4*)h16)[i] = make_uint4(0, 0, 0, 0);
    __syncthreads();

    const int wid = tid >> 6, lane = tid & 63;
    const int ntBase = (wid < 6) ? wid * 5 : 30 + (wid - 6) * 4;
    const int ntCnt  = (wid < 6) ? 5 : 4;
    const int lrow = lane & 15, lk8 = (lane >> 4) * 8;
    const int drow = (lane >> 4) * 4, dcol = lane & 15;

    for (int t = 0; t < 50; ++t) {
        f32x4 a0[5], a1[5];
#pragma unroll
        for (int i = 0; i < 5; ++i) {
            a0[i] = (f32x4){0.f, 0.f, 0.f, 0.f};
            a1[i] = (f32x4){0.f, 0.f, 0.f, 0.f};
        }
#pragma unroll
        for (int kk = 0; kk < 7; ++kk) {
            short8v A0 = *(const short8v*)(&h16[lrow][kk * 32 + lk8]);
            short8v A1 = *(const short8v*)(&h16[16 + lrow][kk * 32 + lk8]);
#pragma unroll
            for (int i = 0; i < 5; ++i) {
                if (i < ntCnt) {
                    const int j = (ntBase + i) * 16 + lrow;
                    short8v B = *(const short8v*)(Wt + (size_t)j * 224 + kk * 32 + lk8);
                    a0[i] = __builtin_amdgcn_mfma_f32_16x16x32_bf16(A0, B, a0[i], 0, 0, 0);
                    a1[i] = __builtin_amdgcn_mfma_f32_16x16x32_bf16(A1, B, a1[i], 0, 0, 0);
                }
            }
        }
#pragma unroll
        for (int i = 0; i < 5; ++i) {
            if (i < ntCnt) {
                const int j = (ntBase + i) * 16 + dcol;
#pragma unroll
                for (int r = 0; r < 4; ++r) {
                    gh[drow + r][j] = a0[i][r];
                    gh[16 + drow + r][j] = a1[i][r];
                }
            }
        }
        __syncthreads();
        for (int task = tid; task < 800; task += 512) {
            const int row = task / 25;
            const int c0 = (task - row * 25) * 8;
            const int grow = row0 + row;
            const __hip_bfloat16* xp = isResp
                ? (xpr16 + ((size_t)grow * 50 + t) * 600)
                : (EPu + (size_t)utt[grow * 50 + t] * 600);
            uint4 xrv = *(const uint4*)(xp + c0);
            uint4 xzv = *(const uint4*)(xp + 200 + c0);
            uint4 xnv = *(const uint4*)(xp + 400 + c0);
            const unsigned xra[4] = { xrv.x, xrv.y, xrv.z, xrv.w };
            const unsigned xza[4] = { xzv.x, xzv.y, xzv.z, xzv.w };
            const unsigned xna[4] = { xnv.x, xnv.y, xnv.z, xnv.w };
            float hn[8];
#pragma unroll
            for (int j = 0; j < 8; ++j) {
                const int c = c0 + j;
                const float xr = (j & 1) ? bh(xra[j >> 1]) : bl(xra[j >> 1]);
                const float xz = (j & 1) ? bh(xza[j >> 1]) : bl(xza[j >> 1]);
                const float xn = (j & 1) ? bh(xna[j >> 1]) : bl(xna[j >> 1]);
                const float rr = sigm(xr + gh[row][c] + bgate[c]);
                const float zz = sigm(xz + gh[row][200 + c] + bgate[200 + c]);
                const float nn = tanhfast(xn + rr * (gh[row][400 + c] + bgate[400 + c]));
                hn[j] = (1.0f - zz) * nn + zz * hf[row][c];
            }
            *(float4*)(&hf[row][c0])     = (float4){hn[0], hn[1], hn[2], hn[3]};
            *(float4*)(&hf[row][c0 + 4]) = (float4){hn[4], hn[5], hn[6], hn[7]};
            uint4 pk;
            pk.x = packbf(hn[0], hn[1]); pk.y = packbf(hn[2], hn[3]);
            pk.z = packbf(hn[4], hn[5]); pk.w = packbf(hn[6], hn[7]);
            *(uint4*)(&h16[row][c0]) = pk;
            *(uint4*)(arch + ((size_t)grow * 50 + t) * 200 + c0) = pk;
        }
        __syncthreads();
    }
}

// ---------------------------------------------------------------------------
// Fused m1/m2 match (MFMA) + conv3x3(2->8)+relu+maxpool3x3 per (b,u).
// Operands staged to LDS as bf16 [64][232] (zero-padded); 4 waves compute the
// 64x64 (used 50x50) product via mfma_f32_16x16x32_bf16 into m[ch] f32 LDS.
// ---------------------------------------------------------------------------
__global__ __launch_bounds__(256)
void match_conv_pool(const int* __restrict__ utt, const float* __restrict__ emb,
                     const __hip_bfloat16* __restrict__ ug16,
                     const __hip_bfloat16* __restrict__ re16,
                     const __hip_bfloat16* __restrict__ rgA16,
                     const float* __restrict__ cw, const float* __restrict__ cb,
                     float* __restrict__ pooled)
{
    const int bu = blockIdx.x, b = bu / 10;
    __shared__ __align__(16) __hip_bfloat16 As[64 * 232];   // 29.7 KB
    __shared__ __align__(16) __hip_bfloat16 Bs[64 * 232];   // 29.7 KB
    __shared__ float m[2][50][50];                          // 20 KB
    __shared__ float w[144];
    __shared__ float bsh[8];
    const int tid = threadIdx.x;
    if (tid < 144) w[tid] = cw[tid];
    if (tid >= 144 && tid < 152) bsh[tid - 144] = cb[tid - 144];

    // ---- stage m1 operands (full 64x29 incl. zero padding) ----
    for (int idx = tid; idx < 64 * 29; idx += 256) {
        int r = idx / 29, q = idx - r * 29;
        uint4 av = make_uint4(0, 0, 0, 0), bv = make_uint4(0, 0, 0, 0);
        if (r < 50 && q < 25) {
            const float* ap = emb + (size_t)utt[bu * 50 + r] * 200 + q * 8;
            float4 f0 = *(const float4*)ap;
            float4 f1 = *(const float4*)(ap + 4);
            av.x = packbf(f0.x, f0.y); av.y = packbf(f0.z, f0.w);
            av.z = packbf(f1.x, f1.y); av.w = packbf(f1.z, f1.w);
            bv = *(const uint4*)(re16 + (size_t)b * 10000 + (size_t)r * 200 + q * 8);
        }
        *(uint4*)(As + r * 232 + q * 8) = av;
        *(uint4*)(Bs + r * 232 + q * 8) = bv;
    }
    __syncthreads();

    const int wid = tid >> 6, lane = tid & 63;
    const int wm = (wid >> 1) * 32, wn = (wid & 1) * 32;
    const int lrow = lane & 15, lk8 = (lane >> 4) * 8;
    const int drow = (lane >> 4) * 4, dcol = lane & 15;

#pragma unroll 1
    for (int ch = 0; ch < 2; ++ch) {
        f32x4 acc00 = {0.f, 0.f, 0.f, 0.f}, acc01 = {0.f, 0.f, 0.f, 0.f};
        f32x4 acc10 = {0.f, 0.f, 0.f, 0.f}, acc11 = {0.f, 0.f, 0.f, 0.f};
#pragma unroll
        for (int kk = 0; kk < 7; ++kk) {
            const int kb = kk * 32 + lk8;
            short8v a0 = *(const short8v*)(As + (wm + lrow) * 232 + kb);
            short8v a1 = *(const short8v*)(As + (wm + 16 + lrow) * 232 + kb);
            short8v b0 = *(const short8v*)(Bs + (wn + lrow) * 232 + kb);
            short8v b1 = *(const short8v*)(Bs + (wn + 16 + lrow) * 232 + kb);
            acc00 = __builtin_amdgcn_mfma_f32_16x16x32_bf16(a0, b0, acc00, 0, 0, 0);
            acc01 = __builtin_amdgcn_mfma_f32_16x16x32_bf16(a0, b1, acc01, 0, 0, 0);
            acc10 = __builtin_amdgcn_mfma_f32_16x16x32_bf16(a1, b0, acc10, 0, 0, 0);
            acc11 = __builtin_amdgcn_mfma_f32_16x16x32_bf16(a1, b1, acc11, 0, 0, 0);
        }
#pragma unroll
        for (int fm = 0; fm < 2; ++fm) {
#pragma unroll
            for (int fn = 0; fn < 2; ++fn) {
                const f32x4 av = (fm == 0) ? (fn == 0 ? acc00 : acc01)
                                           : (fn == 0 ? acc10 : acc11);
                const int gcol = wn + fn * 16 + dcol;
                if (gcol >= 50) continue;
#pragma unroll
                for (int r = 0; r < 4; ++r) {
                    const int grow = wm + fm * 16 + drow + r;
                    if (grow < 50) m[ch][grow][gcol] = av[r];
                }
            }
        }
        __syncthreads();
        if (ch == 0) {
            // restage rows 0..49 (padding stays zero) for m2
            for (int idx = tid; idx < 50 * 25; idx += 256) {
                int r = idx / 25, q = idx - r * 25;
                *(uint4*)(As + r * 232 + q * 8) =
                    *(const uint4*)(ug16 + (size_t)bu * 10000 + (size_t)r * 200 + q * 8);
                *(uint4*)(Bs + r * 232 + q * 8) =
                    *(const uint4*)(rgA16 + (size_t)b * 10000 + (size_t)r * 200 + q * 8);
            }
            __syncthreads();
        }
    }

    // ---- conv + relu + maxpool ----
#pragma unroll
    for (int k = 0; k < 8; ++k) {
        const int o = tid + k * 256;
        const int c = o >> 8, ph = (o >> 4) & 15, pw = o & 15;
        float mx = -1e30f;
#pragma unroll
        for (int p = 0; p < 3; ++p)
#pragma unroll
            for (int q = 0; q < 3; ++q) {
                const int y = ph * 3 + p, x = pw * 3 + q;
                float s = bsh[c];
#pragma unroll
                for (int ci = 0; ci < 2; ++ci)
#pragma unroll
                    for (int dy = 0; dy < 3; ++dy)
#pragma unroll
                        for (int dx = 0; dx < 3; ++dx)
                            s = fmaf(w[(c * 2 + ci) * 9 + dy * 3 + dx],
                                     m[ci][y + dy][x + dx], s);
                s = fmaxf(s, 0.0f);
                mx = fmaxf(mx, s);
            }
        pooled[(size_t)bu * 2048 + o] = mx;
    }
}

// ---------------------------------------------------------------------------
__global__ __launch_bounds__(256)
void final_gru(const float* __restrict__ xpf, const float* __restrict__ WTf,
               const float* __restrict__ bhf, const float* __restrict__ fw,
               const float* __restrict__ fb, float* __restrict__ out)
{
    const int blk = blockIdx.x;
    const int tid = threadIdx.x;
    __shared__ float h[2][201];
    for (int i = tid; i < 402; i += 256) ((float*)h)[i] = 0.0f;
    __syncthreads();
    const int rr = tid / 100;
    const int j0 = 2 * (tid % 100);
    for (int t = 0; t < 10; ++t) {
        float cR[2] = {}, cZ[2] = {}, cN[2] = {};
        if (tid < 200) {
#pragma unroll 2
            for (int e = 0; e < 200; ++e) {
                const float* w = WTf + (size_t)e * 600;
                float2 wr = *(const float2*)(w + j0);
                float2 wz = *(const float2*)(w + 200 + j0);
                float2 wn = *(const float2*)(w + 400 + j0);
                float hv = h[rr][e];
                cR[0] = fmaf(hv, wr.x, cR[0]); cR[1] = fmaf(hv, wr.y, cR[1]);
                cZ[0] = fmaf(hv, wz.x, cZ[0]); cZ[1] = fmaf(hv, wz.y, cZ[1]);
                cN[0] = fmaf(hv, wn.x, cN[0]); cN[1] = fmaf(hv, wn.y, cN[1]);
            }
        }
        __syncthreads();
        if (tid < 200) {
            const float* xp = xpf + ((size_t)(blk * 2 + rr) * 10 + t) * 600;
#pragma unroll
            for (int j = 0; j < 2; ++j) {
                const int c = j0 + j;
                float rrg = sigm(xp[c] + cR[j] + bhf[c]);
                float zz = sigm(xp[200 + c] + cZ[j] + bhf[200 + c]);
                float nn = tanhfast(xp[400 + c] + rrg * (cN[j] + bhf[400 + c]));
                h[rr][c] = (1.0f - zz) * nn + zz * h[rr][c];
            }
        }
        __syncthreads();
    }
    if (tid < 2) {
        float s = fb[0];
        for (int k = 0; k < 200; ++k) s = fmaf(h[tid][k], fw[k], s);
        out[blk * 2 + tid] = sigm(s);
    }
}

__global__ __launch_bounds__(256)
void fill_out(float* __restrict__ out)
{
    int i = blockIdx.x * 256 + threadIdx.x;
    if (i < 512) out[i] = 0.0f;
}

// ---------------------------------------------------------------------------
extern "C" void kernel_launch(void* const* d_in, const int* in_sizes, int n_in,
                              void* d_out, int out_size, void* d_ws, size_t ws_size,
                              hipStream_t stream)
{
    const int*   utt    = (const int*)d_in[0];
    const int*   resp   = (const int*)d_in[1];
    const float* emb    = (const float*)d_in[2];
    const float* W_ih_u = (const float*)d_in[3];
    const float* W_hh_u = (const float*)d_in[4];
    const float* b_ih_u = (const float*)d_in[5];
    const float* b_hh_u = (const float*)d_in[6];
    const float* W_ih_r = (const float*)d_in[7];
    const float* W_hh_r = (const float*)d_in[8];
    const float* b_ih_r = (const float*)d_in[9];
    const float* b_hh_r = (const float*)d_in[10];
    const float* conv_w = (const float*)d_in[11];
    const float* conv_b = (const float*)d_in[12];
    const float* lin_w  = (const float*)d_in[13];
    const float* lin_b  = (const float*)d_in[14];
    const float* Amat   = (const float*)d_in[15];
    const float* W_ih_f = (const float*)d_in[16];
    const float* W_hh_f = (const float*)d_in[17];
    const float* b_ih_f = (const float*)d_in[18];
    const float* b_hh_f = (const float*)d_in[19];
    const float* flin_w = (const float*)d_in[20];
    const float* flin_b = (const float*)d_in[21];
    float* out = (float*)d_out;
    float* ws  = (float*)d_ws;

    size_t off = 0;
    auto alloc = [&](size_t n) { float* p = ws + off; off += (n + 63) & ~((size_t)63); return p; };
    float* WT_f   = alloc(120000);
    float* Wu16f  = alloc(68096);      // [608,224] bf16
    float* Wr16f  = alloc(68096);      // [608,224] bf16
    float* re16f  = alloc(2560000);    // [25600,200] bf16
    float* EPuf   = alloc(15000000);   // [50000,600] bf16; post-scan: pooled
    float* xprf   = alloc(7680000);    // [25600,600] bf16; post-scan: mv/xpf
    float* ug16f  = alloc(25600000);   // [5120,50,200] bf16
    float* rg16f  = alloc(2560000);    // [512,50,200] bf16
    float* rgA16f = alloc(2560000);    // [25600,200] bf16
    // total ~56.2M floats = 225 MB

    if (off * sizeof(float) > ws_size) {
        hipLaunchKernelGGL(fill_out, dim3(2), dim3(256), 0, stream, out);
        return;
    }

    __hip_bfloat16* Wu16  = (__hip_bfloat16*)Wu16f;
    __hip_bfloat16* Wr16  = (__hip_bfloat16*)Wr16f;
    __hip_bfloat16* re16  = (__hip_bfloat16*)re16f;
    __hip_bfloat16* EPu   = (__hip_bfloat16*)EPuf;
    __hip_bfloat16* xpr16 = (__hip_bfloat16*)xprf;
    __hip_bfloat16* ug16  = (__hip_bfloat16*)ug16f;
    __hip_bfloat16* rg16  = (__hip_bfloat16*)rg16f;
    __hip_bfloat16* rgA16 = (__hip_bfloat16*)rgA16f;
    float* pooled = EPuf;              // [5120,2048] f32 (EPu dead after scan)
    float* mv     = xprf;              // [5120,50] f32  (xpr dead after scan)
    float* xpf    = xprf + 400000;     // [5120,600] f32

    // 1. transpose W_hh_f (final GRU) + pack scan weights bf16
    hipLaunchKernelGGL(transpose_wf, dim3(469), dim3(256), 0, stream, W_hh_f, WT_f);
    hipLaunchKernelGGL(pack_whh, dim3(532), dim3(256), 0, stream,
                       W_hh_u, W_hh_r, Wu16, Wr16);
    // 2. response embedding gather (bf16)
    hipLaunchKernelGGL(gather_re16, dim3(10000), dim3(256), 0, stream, resp, emb, re16);
    // 3. EPu = bf16(emb @ W_ih_u^T + b_ih_u) for the whole vocab  [MFMA]
    hipLaunchKernelGGL(gemm_mfma, dim3(782, 10), dim3(256), 0, stream,
                       (const void*)emb, 0, (const int*)nullptr, W_ih_u, b_ih_u,
                       EPu, 50000, 600);
    // 4. xpr16 = bf16(emb[resp] @ W_ih_r^T + b_ih_r)  [MFMA]
    hipLaunchKernelGGL(gemm_mfma, dim3(400, 10), dim3(256), 0, stream,
                       (const void*)emb, 0, resp, W_ih_r, b_ih_r,
                       xpr16, 25600, 600);
    // 5. persistent MFMA dual-GRU scan
    hipLaunchKernelGGL(scan_gru_mfma, dim3(176), dim3(512), 0, stream,
                       utt, EPu, xpr16, Wu16, Wr16, b_hh_u, b_hh_r, ug16, rg16);
    // 6. rgA16 = bf16(rg @ Amat^T)  [MFMA]
    hipLaunchKernelGGL(gemm_mfma, dim3(400, 4), dim3(256), 0, stream,
                       (const void*)rg16, 1, (const int*)nullptr, Amat,
                       (const float*)nullptr, rgA16, 25600, 200);
    // 7. fused match (MFMA) + conv + pool
    hipLaunchKernelGGL(match_conv_pool, dim3(5120), dim3(256), 0, stream,
                       utt, emb, ug16, re16, rgA16, conv_w, conv_b, pooled);
    // 8. mv = tanh(pooled @ lin_w^T + lin_b)
    hipLaunchKernelGGL(gemm_tn, dim3(80, 1), dim3(256), 0, stream,
                       pooled, 0, (const int*)nullptr, 1, 0, lin_w, lin_b,
                       mv, 0, 5120, 50, 2048, 1);
    // 9. xpf = mv @ W_ih_f^T + b_ih_f
    hipLaunchKernelGGL(gemm_tn, dim3(80, 10), dim3(256), 0, stream,
                       mv, 0, (const int*)nullptr, 1, 0, W_ih_f, b_ih_f,
                       xpf, 0, 5120, 600, 50, 0);
    // 10. final GRU + logit + sigmoid
    hipLaunchKernelGGL(final_gru, dim3(256), dim3(256), 0, stream,
                       xpf, WT_f, b_hh_f, flin_w, flin_b, out);
}